// Round 9
// baseline (161.159 us; speedup 1.0000x reference)
//
#include <hip/hip_runtime.h>
#include <hip/hip_bf16.h>

// Problem constants
#define NB    16
#define NC    1024
#define NF    4096
#define MROWS 65536      // NB*NF
#define CIN   256
#define CSK   128
#define DIN   384        // CIN + CSK
#define CHID  256
#define BN_EPS 1e-5f

typedef __attribute__((ext_vector_type(8))) short bf16x8;
typedef __attribute__((ext_vector_type(4))) float f32x4;

__device__ __forceinline__ unsigned short f2bfu(float f) {
  __hip_bfloat16 h = __float2bfloat16(f);
  return __builtin_bit_cast(unsigned short, h);
}
__device__ __forceinline__ float bfu2f(unsigned short u) {
  unsigned int w = ((unsigned int)u) << 16;
  return __builtin_bit_cast(float, w);
}
__device__ __forceinline__ unsigned int pack2(float lo, float hi) {
  return ((unsigned int)f2bfu(hi) << 16) | (unsigned int)f2bfu(lo);
}

__device__ __forceinline__ void load_lds16(const void* g, void* lds) {
  __builtin_amdgcn_global_load_lds(
      (const __attribute__((address_space(1))) unsigned int*)g,
      (__attribute__((address_space(3))) unsigned int*)lds, 16, 0, 0);
}

// sorted top-3 insert, strict-< (valid when inserted index > all held indices)
__device__ __forceinline__ void ins3(float d2, int j, float& b0, float& b1,
                                     float& b2v, int& i0, int& i1, int& i2) {
  const bool c0 = d2 < b0, c1 = d2 < b1, c2 = d2 < b2v;
  const float nb1 = __builtin_amdgcn_fmed3f(d2, b0, b1);
  const float nb2 = __builtin_amdgcn_fmed3f(d2, b1, b2v);
  i2  = c1 ? i1 : (c2 ? j : i2);
  i1  = c0 ? i0 : (c1 ? j : i1);
  i0  = c0 ? j : i0;
  b2v = nb2;
  b1  = nb1;
  b0  = fminf(d2, b0);
}

// sorted top-3 insert with (d, idx) lexicographic tiebreak — order-independent
__device__ __forceinline__ void ins3tb(float d, int j, float& b0, float& b1,
                                       float& b2v, int& i0, int& i1, int& i2) {
  const bool c0 = (d < b0) || (d == b0 && j < i0);
  const bool c1 = (d < b1) || (d == b1 && j < i1);
  const bool c2 = (d < b2v) || (d == b2v && j < i2);
  const float nb1 = __builtin_amdgcn_fmed3f(d, b0, b1);
  const float nb2 = __builtin_amdgcn_fmed3f(d, b1, b2v);
  i2  = c1 ? i1 : (c2 ? j : i2);
  i1  = c0 ? i0 : (c1 ? j : i1);
  i0  = c0 ? j : i0;
  b2v = nb2;
  b1  = nb1;
  b0  = fminf(d, b0);
}

// ---------------------------------------------------------------------------
// D1: xb = bf16(x) [blocks 0..1023], W1at transpose [1024..1279],
//     stats zero [1280].
// ---------------------------------------------------------------------------
__global__ __launch_bounds__(256) void prep1_kernel(
    const float* __restrict__ x, const float* __restrict__ W1,
    __hip_bfloat16* __restrict__ xb, __hip_bfloat16* __restrict__ W1at,
    float* __restrict__ stats) {
  const int tid = threadIdx.x, blk = blockIdx.x;
  if (blk < 1024) {                       // xb: 16 elems/thread
    const size_t base = (size_t)blk * 4096 + (size_t)tid * 16;
    const float4* src = (const float4*)(x + base);
    const float4 a = src[0], b = src[1], c = src[2], d = src[3];
    uint4 u1, u2;
    u1.x = pack2(a.x, a.y); u1.y = pack2(a.z, a.w);
    u1.z = pack2(b.x, b.y); u1.w = pack2(b.z, b.w);
    u2.x = pack2(c.x, c.y); u2.y = pack2(c.z, c.w);
    u2.z = pack2(d.x, d.y); u2.w = pack2(d.z, d.w);
    uint4* dst = (uint4*)(xb + base);
    dst[0] = u1; dst[1] = u2;
  } else if (blk < 1280) {                // W1at[n][k] = W1[k][n], k<256
    const int k = blk - 1024;
    W1at[(size_t)tid * 256 + k] = __float2bfloat16(W1[(size_t)k * CHID + tid]);
  } else {
    for (int q = tid; q < 1024; q += 256) stats[q] = 0.f;
  }
}

// ---------------------------------------------------------------------------
// D2 mixed dispatch (512 thr):
//  [0,1024)    kNN scan -> recA (w0,w1,w2,j0) + recB (j1,j2)
//  [1024,1152) gemmB: y = xb @ W1at^T (f32 out) — overlaps scan on MFMA pipe
//  [1152,3200) xsb = bf16(x_skip)
//  [3200,3264) W1bt[n][k] = W1[256+k][n]
// ---------------------------------------------------------------------------
__global__ __launch_bounds__(512, 4) void scan_gemmB_kernel(
    const float* __restrict__ pos, const float* __restrict__ pos_skip,
    const float* __restrict__ x_skip, const float* __restrict__ W1,
    const __hip_bfloat16* __restrict__ xb,
    const __hip_bfloat16* __restrict__ W1at,
    __hip_bfloat16* __restrict__ xsb, __hip_bfloat16* __restrict__ W1bt,
    float4* __restrict__ recA, int2* __restrict__ recB,
    float* __restrict__ y) {
  __shared__ __align__(16) char smem[49152];
  const int tid = threadIdx.x, lane = tid & 63, wid = tid >> 6;
  const int blk = blockIdx.x;

  if (blk < 1024) {                       // ---------------- scan role
    float4* cposI = (float4*)smem;        // swizzled slots, 16KB
    const int f0 = blk * 64;
    const int b = f0 >> 12;
    const float* pb = pos + (size_t)b * NC * 3;
    for (int j = tid; j < NC; j += 512) {
      const int slot = ((j & 127) << 3) | ((j >> 7) ^ (j & 7));
      cposI[slot] = make_float4(pb[3 * j], pb[3 * j + 1], pb[3 * j + 2], 0.f);
    }
    __syncthreads();

    const int ll = lane & 7;
    const int pl = wid * 8 + (lane >> 3);   // 0..63
    const int f = f0 + pl;
    const float fx = pos_skip[(size_t)f * 3];
    const float fy = pos_skip[(size_t)f * 3 + 1];
    const float fz = pos_skip[(size_t)f * 3 + 2];
    const int jb = ll * 128;

    float a0 = 3.4e38f, a1 = 3.4e38f, a2 = 3.4e38f;
    float c0 = 3.4e38f, c1 = 3.4e38f, c2 = 3.4e38f;
    int ia0 = 0, ia1 = 0, ia2 = 0, ic0 = 0, ic1 = 0, ic2 = 0;
#pragma unroll 8
    for (int t = 0; t < 64; ++t) {
      const int sw = ll ^ (t & 7);
      const float4 pA = cposI[t * 8 + sw];
      const float4 pB = cposI[(t + 64) * 8 + sw];
      const float dxA = __fsub_rn(fx, pA.x), dyA = __fsub_rn(fy, pA.y),
                  dzA = __fsub_rn(fz, pA.z);
      const float dxB = __fsub_rn(fx, pB.x), dyB = __fsub_rn(fy, pB.y),
                  dzB = __fsub_rn(fz, pB.z);
      const float d2A = __fadd_rn(
          __fadd_rn(__fmul_rn(dxA, dxA), __fmul_rn(dyA, dyA)),
          __fmul_rn(dzA, dzA));
      const float d2B = __fadd_rn(
          __fadd_rn(__fmul_rn(dxB, dxB), __fmul_rn(dyB, dyB)),
          __fmul_rn(dzB, dzB));
      ins3(d2A, jb + t,      a0, a1, a2, ia0, ia1, ia2);
      ins3(d2B, jb + 64 + t, c0, c1, c2, ic0, ic1, ic2);
    }
    ins3(c0, ic0, a0, a1, a2, ia0, ia1, ia2);
    ins3(c1, ic1, a0, a1, a2, ia0, ia1, ia2);
    ins3(c2, ic2, a0, a1, a2, ia0, ia1, ia2);

#pragma unroll
    for (int mm = 1; mm <= 4; mm <<= 1) {
      const float o0 = __shfl_xor(a0, mm);
      const float o1 = __shfl_xor(a1, mm);
      const float o2 = __shfl_xor(a2, mm);
      const int oj0 = __shfl_xor(ia0, mm);
      const int oj1 = __shfl_xor(ia1, mm);
      const int oj2 = __shfl_xor(ia2, mm);
      ins3tb(o0, oj0, a0, a1, a2, ia0, ia1, ia2);
      ins3tb(o1, oj1, a0, a1, a2, ia0, ia1, ia2);
      ins3tb(o2, oj2, a0, a1, a2, ia0, ia1, ia2);
    }

    if (ll == 0) {
      float w0 = 1.f / fmaxf(a0, 1e-16f);
      float w1 = 1.f / fmaxf(a1, 1e-16f);
      float w2 = 1.f / fmaxf(a2, 1e-16f);
      const float inv = 1.f / (w0 + w1 + w2);
      recA[f] = make_float4(w0 * inv, w1 * inv, w2 * inv,
                            __int_as_float(ia0));
      recB[f] = make_int2(ia1, ia2);
    }
    return;
  }

  if (blk < 1152) {                       // ---------------- gemmB role
    const int bm = blk - 1024;            // 0..127
    const int wr = wid >> 2, wc = wid & 3;
    const int la = lane & 15, lk = lane >> 4;
    f32x4 acc[4][4] = {};
    const int rA = tid >> 2;
    const int c8 = (tid & 3) * 8;
    const __hip_bfloat16* gA  = xb   + (size_t)(bm * 128 + rA) * 256 + c8;
    const __hip_bfloat16* gB0 = W1at + (size_t)rA * 256 + c8;
    const __hip_bfloat16* gB1 = W1at + (size_t)(128 + rA) * 256 + c8;
    char* ldsA  = smem + wid * 1024;
    char* ldsB0 = smem + 16384 + wid * 1024;

    load_lds16(gA,  ldsA);
    load_lds16(gB0, ldsB0);
    load_lds16(gB1, ldsB0 + 8192);
    __syncthreads();

    for (int it = 0; it < 8; ++it) {
      const int cur = it & 1, nxt = cur ^ 1;
      if (it < 7) {
        const int k1 = (it + 1) * 32;
        load_lds16(gA  + k1, smem + nxt * 8192 + wid * 1024);
        load_lds16(gB0 + k1, smem + 16384 + nxt * 16384 + wid * 1024);
        load_lds16(gB1 + k1, smem + 16384 + nxt * 16384 + wid * 1024 + 8192);
      }
      const __hip_bfloat16* Acur = (const __hip_bfloat16*)smem + cur * 4096;
      const __hip_bfloat16* Bcur =
          (const __hip_bfloat16*)(smem + 16384) + cur * 8192;
      bf16x8 af[4], bfr[4];
#pragma unroll
      for (int m = 0; m < 4; ++m)
        af[m] = *(const bf16x8*)(Acur + (wr * 64 + m * 16 + la) * 32 + lk * 8);
#pragma unroll
      for (int n = 0; n < 4; ++n)
        bfr[n] = *(const bf16x8*)(Bcur + (wc * 64 + n * 16 + la) * 32 + lk * 8);
#pragma unroll
      for (int m = 0; m < 4; ++m)
#pragma unroll
        for (int n = 0; n < 4; ++n)
          acc[m][n] = __builtin_amdgcn_mfma_f32_16x16x32_bf16(
              af[m], bfr[n], acc[m][n], 0, 0, 0);
      __syncthreads();
    }

    const int rowBase = bm * 128 + wr * 64 + lk * 4;
#pragma unroll
    for (int n = 0; n < 4; ++n) {
      const int col = wc * 64 + n * 16 + la;
#pragma unroll
      for (int m = 0; m < 4; ++m)
#pragma unroll
        for (int j = 0; j < 4; ++j)
          y[(size_t)(rowBase + m * 16 + j) * 256 + col] = acc[m][n][j];
    }
    return;
  }

  if (blk < 3200) {                       // ---------------- xsb convert
    const size_t base = (size_t)(blk - 1152) * 4096 + (size_t)tid * 8;
    const float4* src = (const float4*)(x_skip + base);
    const float4 a = src[0], b4 = src[1];
    uint4 u;
    u.x = pack2(a.x, a.y);  u.y = pack2(a.z, a.w);
    u.z = pack2(b4.x, b4.y); u.w = pack2(b4.z, b4.w);
    *(uint4*)(xsb + base) = u;
    return;
  }

  {                                       // ---------------- W1bt role
    const int q = blk - 3200;             // 0..63
    const int n = q * 4 + (tid >> 7);     // 0..255
    const int k = tid & 127;              // 0..127
    W1bt[(size_t)n * 128 + k] =
        __float2bfloat16(W1[(size_t)(256 + k) * CHID + n]);
  }
}

// ---------------------------------------------------------------------------
// D3: z1 = relu(xsb @ W1bt^T + interp(y) + b1), bf16 out + BN1 stats.
// 64x256 tile, K=128, 8 waves (2x4 of 32x64); interp rows gathered from y
// (L2/L3-resident) into LDS bf16 before the MFMA loop.
// ---------------------------------------------------------------------------
__global__ __launch_bounds__(512, 4) void gemm_skip_interp_kernel(
    const __hip_bfloat16* __restrict__ xsb,
    const __hip_bfloat16* __restrict__ W1bt,
    const float* __restrict__ b1, const float4* __restrict__ recA,
    const int2* __restrict__ recB, const float* __restrict__ y,
    __hip_bfloat16* __restrict__ z1, float* __restrict__ gsum,
    float* __restrict__ gsq) {
  __shared__ __hip_bfloat16 As[2 * 64 * 32];    // 8 KB
  __shared__ __hip_bfloat16 Bs[2 * 256 * 32];   // 32 KB
  __shared__ unsigned short itp[64 * 256];      // 32 KB
  __shared__ float lw[64][3];
  __shared__ int lj[64][3];
  __shared__ float ssum[256], ssq[256];
  const int tid = threadIdx.x, lane = tid & 63, wid = tid >> 6;
  const int bm = blockIdx.x;
  const int bb = (bm * 64) >> 12;               // batch

  if (tid < 256) { ssum[tid] = 0.f; ssq[tid] = 0.f; }
  if (tid < 64) {
    const float4 ra = recA[bm * 64 + tid];
    const int2 rb = recB[bm * 64 + tid];
    lw[tid][0] = ra.x; lw[tid][1] = ra.y; lw[tid][2] = ra.z;
    lj[tid][0] = __float_as_int(ra.w); lj[tid][1] = rb.x; lj[tid][2] = rb.y;
  }

  const int rA = tid >> 2, c8 = (tid & 3) * 8;
  const __hip_bfloat16* gA  = xsb + (size_t)(bm * 64 + rA) * 128 + c8;
  const __hip_bfloat16* gB0 = W1bt + (size_t)rA * 128 + c8;
  const __hip_bfloat16* gB1 = W1bt + (size_t)(128 + rA) * 128 + c8;
  char* ldsB0 = (char*)Bs + wid * 1024;
  if (tid < 256) load_lds16(gA, (char*)As + wid * 1024);
  load_lds16(gB0, ldsB0);
  load_lds16(gB1, ldsB0 + 8192);
  __syncthreads();     // lw/lj visible; K-tile 0 staged

  // gather interp rows (wave w handles rows w*8 .. w*8+7)
  for (int rr = 0; rr < 8; ++rr) {
    const int r = wid * 8 + rr;
    const float w0 = lw[r][0], w1 = lw[r][1], w2 = lw[r][2];
    const float4* y0 = (const float4*)(y + (size_t)(bb * NC + lj[r][0]) * 256);
    const float4* y1 = (const float4*)(y + (size_t)(bb * NC + lj[r][1]) * 256);
    const float4* y2 = (const float4*)(y + (size_t)(bb * NC + lj[r][2]) * 256);
    const float4 A4 = y0[lane], B4 = y1[lane], C4 = y2[lane];
    float4 v;
    v.x = w0 * A4.x + w1 * B4.x + w2 * C4.x;
    v.y = w0 * A4.y + w1 * B4.y + w2 * C4.y;
    v.z = w0 * A4.z + w1 * B4.z + w2 * C4.z;
    v.w = w0 * A4.w + w1 * B4.w + w2 * C4.w;
    uint2 o;
    o.x = pack2(v.x, v.y);
    o.y = pack2(v.z, v.w);
    *(uint2*)((char*)itp + r * 512 + lane * 8) = o;
  }
  // itp writes complete before epilogue reads (MFMA loop barriers cover it)

  const int wr = wid >> 2, wc = wid & 3;
  const int la = lane & 15, lk = lane >> 4;
  f32x4 acc[2][4] = {};
  for (int it = 0; it < 4; ++it) {
    const int cur = it & 1, nxt = cur ^ 1;
    if (it < 3) {
      const int k1 = (it + 1) * 32;
      if (tid < 256) load_lds16(gA + k1, (char*)As + nxt * 4096 + wid * 1024);
      load_lds16(gB0 + k1, (char*)Bs + nxt * 16384 + wid * 1024);
      load_lds16(gB1 + k1, (char*)Bs + nxt * 16384 + wid * 1024 + 8192);
    }
    const __hip_bfloat16* Acur = As + cur * 2048;
    const __hip_bfloat16* Bcur = Bs + cur * 8192;
    bf16x8 af[2], bfr[4];
#pragma unroll
    for (int m = 0; m < 2; ++m)
      af[m] = *(const bf16x8*)(Acur + (wr * 32 + m * 16 + la) * 32 + lk * 8);
#pragma unroll
    for (int n = 0; n < 4; ++n)
      bfr[n] = *(const bf16x8*)(Bcur + (wc * 64 + n * 16 + la) * 32 + lk * 8);
#pragma unroll
    for (int m = 0; m < 2; ++m)
#pragma unroll
      for (int n = 0; n < 4; ++n)
        acc[m][n] = __builtin_amdgcn_mfma_f32_16x16x32_bf16(
            af[m], bfr[n], acc[m][n], 0, 0, 0);
    __syncthreads();
  }

  const int rowTop = bm * 64;
#pragma unroll
  for (int n = 0; n < 4; ++n) {
    const int col = wc * 64 + n * 16 + la;
    const float bs = b1[col];
    float ls = 0.f, ls2 = 0.f;
#pragma unroll
    for (int m = 0; m < 2; ++m) {
#pragma unroll
      for (int j = 0; j < 4; ++j) {
        const int lr = wr * 32 + m * 16 + lk * 4 + j;
        const float iv = bfu2f(itp[lr * 256 + col]);
        float v = acc[m][n][j] + bs + iv;
        v = fmaxf(v, 0.f);
        ls += v; ls2 += v * v;
        z1[(size_t)(rowTop + lr) * 256 + col] = __float2bfloat16(v);
      }
    }
    atomicAdd(&ssum[col], ls);
    atomicAdd(&ssq[col], ls2);
  }
  __syncthreads();
  if (tid < 256) {
    atomicAdd(&gsum[tid], ssum[tid]);
    atomicAdd(&gsq[tid], ssq[tid]);
  }
}

// ---------------------------------------------------------------------------
// Fused BN1-finalize + W2 fold + b2 fold.
// ---------------------------------------------------------------------------
__global__ __launch_bounds__(256) void prep_w2b2_kernel(
    const float* __restrict__ W2, const float* __restrict__ stats,
    const float* __restrict__ g1, const float* __restrict__ be1,
    const float* __restrict__ b2, __hip_bfloat16* __restrict__ W2t,
    float* __restrict__ b2p) {
  const int n = blockIdx.x, c = threadIdx.x;
  const int wid = c >> 6, lane = c & 63;
  const float m = stats[c] * (1.f / MROWS);
  const float var = stats[256 + c] * (1.f / MROWS) - m * m;
  const float sc = g1[c] * rsqrtf(var + BN_EPS);
  const float sh = be1[c] - m * sc;
  const float w = W2[(size_t)c * CHID + n];
  W2t[(size_t)n * CHID + c] = __float2bfloat16(sc * w);
  float p = sh * w;
#pragma unroll
  for (int off = 32; off > 0; off >>= 1) p += __shfl_down(p, off);
  __shared__ float red4[4];
  if (lane == 0) red4[wid] = p;
  __syncthreads();
  if (c == 0) b2p[n] = red4[0] + red4[1] + red4[2] + red4[3] + b2[n];
}

// ---------------------------------------------------------------------------
// GEMM2: z2 = relu(z1 @ W2t^T + b2p), bf16 out + BN2 stats (proven r8).
// ---------------------------------------------------------------------------
template<int KD>
__global__ __launch_bounds__(512) void gemm_bias_relu(
    const __hip_bfloat16* __restrict__ A, const __hip_bfloat16* __restrict__ Bt,
    const float* __restrict__ bias, __hip_bfloat16* __restrict__ out,
    float* __restrict__ gsum, float* __restrict__ gsq) {
  __shared__ __hip_bfloat16 As[2 * 128 * 32];
  __shared__ __hip_bfloat16 Bs[2 * 256 * 32];
  __shared__ float ssum[256], ssq[256];
  const int tid = threadIdx.x;
  const int wid = tid >> 6, lane = tid & 63;
  const int bm = blockIdx.x;
  const int wr = wid >> 2, wc = wid & 3;
  const int la = lane & 15, lk = lane >> 4;

  if (tid < 256) { ssum[tid] = 0.f; ssq[tid] = 0.f; }

  f32x4 acc[4][4] = {};

  const int rA = tid >> 2;
  const int c8 = (tid & 3) * 8;
  const __hip_bfloat16* gA  = A  + (size_t)(bm * 128 + rA) * KD + c8;
  const __hip_bfloat16* gB0 = Bt + (size_t)rA * KD + c8;
  const __hip_bfloat16* gB1 = Bt + (size_t)(128 + rA) * KD + c8;
  char* ldsA  = (char*)As + wid * 1024;
  char* ldsB0 = (char*)Bs + wid * 1024;

  load_lds16(gA,  ldsA);
  load_lds16(gB0, ldsB0);
  load_lds16(gB1, ldsB0 + 8192);
  __syncthreads();

  const int nIter = KD / 32;
  for (int it = 0; it < nIter; ++it) {
    const int cur = it & 1, nxt = cur ^ 1;
    if (it + 1 < nIter) {
      const int k1 = (it + 1) * 32;
      load_lds16(gA  + k1, ldsA  + nxt * 8192);
      load_lds16(gB0 + k1, ldsB0 + nxt * 16384);
      load_lds16(gB1 + k1, ldsB0 + nxt * 16384 + 8192);
    }
    const __hip_bfloat16* Acur = As + cur * 4096;
    const __hip_bfloat16* Bcur = Bs + cur * 8192;
    bf16x8 af[4], bfr[4];
#pragma unroll
    for (int m = 0; m < 4; ++m)
      af[m] = *(const bf16x8*)(Acur + (wr * 64 + m * 16 + la) * 32 + lk * 8);
#pragma unroll
    for (int n = 0; n < 4; ++n)
      bfr[n] = *(const bf16x8*)(Bcur + (wc * 64 + n * 16 + la) * 32 + lk * 8);
#pragma unroll
    for (int m = 0; m < 4; ++m)
#pragma unroll
      for (int n = 0; n < 4; ++n)
        acc[m][n] = __builtin_amdgcn_mfma_f32_16x16x32_bf16(
            af[m], bfr[n], acc[m][n], 0, 0, 0);
    __syncthreads();
  }

  const int rowBase = bm * 128 + wr * 64 + lk * 4;
#pragma unroll
  for (int n = 0; n < 4; ++n) {
    const int col = wc * 64 + n * 16 + la;
    const float bs = bias[col];
    float ls = 0.f, ls2 = 0.f;
#pragma unroll
    for (int m = 0; m < 4; ++m) {
      const int row = rowBase + m * 16;
#pragma unroll
      for (int j = 0; j < 4; ++j) {
        float v = acc[m][n][j] + bs;
        v = fmaxf(v, 0.f);
        ls += v; ls2 += v * v;
        out[(size_t)(row + j) * 256 + col] = __float2bfloat16(v);
      }
    }
    atomicAdd(&ssum[col], ls);
    atomicAdd(&ssq[col], ls2);
  }
  __syncthreads();
  if (tid < 256) {
    atomicAdd(&gsum[tid], ssum[tid]);
    atomicAdd(&gsq[tid], ssq[tid]);
  }
}

// ---------------------------------------------------------------------------
// bn apply (with inlined BN2 finalize): read bf16 z2, write f32 out.
// ---------------------------------------------------------------------------
__global__ __launch_bounds__(256) void bn_apply_kernel(
    const __hip_bfloat16* __restrict__ Z, const float* __restrict__ stats,
    const float* __restrict__ g2, const float* __restrict__ be2,
    float* __restrict__ out) {
  __shared__ float ssc[256], ssh[256];
  const int t = threadIdx.x;
  {
    const float m = stats[t] * (1.f / MROWS);
    const float var = stats[256 + t] * (1.f / MROWS) - m * m;
    const float sc = g2[t] * rsqrtf(var + BN_EPS);
    ssc[t] = sc;
    ssh[t] = be2[t] - m * sc;
  }
  __syncthreads();
  const size_t i8 = (size_t)blockIdx.x * 256 + t;
  const uint4 raw = ((const uint4*)Z)[i8];
  const int c0 = (int)((i8 * 8) & 255);
  const float4 scA = *(const float4*)(ssc + c0);
  const float4 scB = *(const float4*)(ssc + c0 + 4);
  const float4 shA = *(const float4*)(ssh + c0);
  const float4 shB = *(const float4*)(ssh + c0 + 4);
  float4 oa, ob;
  oa.x = bfu2f((unsigned short)(raw.x & 0xffff)) * scA.x + shA.x;
  oa.y = bfu2f((unsigned short)(raw.x >> 16))    * scA.y + shA.y;
  oa.z = bfu2f((unsigned short)(raw.y & 0xffff)) * scA.z + shA.z;
  oa.w = bfu2f((unsigned short)(raw.y >> 16))    * scA.w + shA.w;
  ob.x = bfu2f((unsigned short)(raw.z & 0xffff)) * scB.x + shB.x;
  ob.y = bfu2f((unsigned short)(raw.z >> 16))    * scB.y + shB.y;
  ob.z = bfu2f((unsigned short)(raw.w & 0xffff)) * scB.z + shB.z;
  ob.w = bfu2f((unsigned short)(raw.w >> 16))    * scB.w + shB.w;
  ((float4*)(out))[i8 * 2]     = oa;
  ((float4*)(out))[i8 * 2 + 1] = ob;
}

// ---------------------------------------------------------------------------
extern "C" void kernel_launch(void* const* d_in, const int* in_sizes, int n_in,
                              void* d_out, int out_size, void* d_ws,
                              size_t ws_size, hipStream_t stream) {
  (void)in_sizes; (void)n_in; (void)out_size; (void)ws_size;
  const float* x        = (const float*)d_in[0];
  const float* pos      = (const float*)d_in[1];
  const float* x_skip   = (const float*)d_in[3];
  const float* pos_skip = (const float*)d_in[4];
  const float* W1  = (const float*)d_in[6];
  const float* b1  = (const float*)d_in[7];
  const float* g1  = (const float*)d_in[8];
  const float* be1 = (const float*)d_in[9];
  const float* W2  = (const float*)d_in[10];
  const float* b2  = (const float*)d_in[11];
  const float* g2  = (const float*)d_in[12];
  const float* be2 = (const float*)d_in[13];
  float* out = (float*)d_out;

  char* ws = (char*)d_ws;
  // Workspace layout (bytes). z2 aliases xb/xsb/y (all dead after D3).
  __hip_bfloat16* xb   = (__hip_bfloat16*)(ws);                  //  8,388,608
  __hip_bfloat16* z2   = (__hip_bfloat16*)(ws);                  // 33,554,432 (alias)
  __hip_bfloat16* xsb  = (__hip_bfloat16*)(ws + 8388608);        // 16,777,216
  float*          y    = (float*)(ws + 25165824);                // 16,777,216
  __hip_bfloat16* z1   = (__hip_bfloat16*)(ws + 41943040);       // 33,554,432
  __hip_bfloat16* W1at = (__hip_bfloat16*)(ws + 75497472);       //    131,072
  __hip_bfloat16* W1bt = (__hip_bfloat16*)(ws + 75628544);       //     65,536
  __hip_bfloat16* W2t  = (__hip_bfloat16*)(ws + 75694080);       //    131,072
  float4*         recA = (float4*)(ws + 75825152);               //  1,048,576
  int2*           recB = (int2*)(ws + 76873728);                 //    524,288
  float*          b2p  = (float*)(ws + 77398016);                //      1,024
  float*          stats= (float*)(ws + 77399040);                //      4,096

  prep1_kernel<<<1281, 256, 0, stream>>>(x, W1, xb, W1at, stats);
  scan_gemmB_kernel<<<3264, 512, 0, stream>>>(pos, pos_skip, x_skip, W1, xb,
                                              W1at, xsb, W1bt, recA, recB, y);
  gemm_skip_interp_kernel<<<1024, 512, 0, stream>>>(xsb, W1bt, b1, recA, recB,
                                                    y, z1, stats, stats + 256);
  prep_w2b2_kernel<<<256, 256, 0, stream>>>(W2, stats, g1, be1, b2, W2t, b2p);
  gemm_bias_relu<CHID><<<512, 512, 0, stream>>>(z1, W2t, b2p, z2,
                                                stats + 512, stats + 768);
  bn_apply_kernel<<<8192, 256, 0, stream>>>(z2, stats + 512, g2, be2, out);
}